// Round 4
// baseline (320.087 us; speedup 1.0000x reference)
//
#include <hip/hip_runtime.h>
#include <hip/hip_bf16.h>

typedef __bf16 bf16x8 __attribute__((ext_vector_type(8)));
typedef __bf16 bf16x4 __attribute__((ext_vector_type(4)));
typedef float  f32x4  __attribute__((ext_vector_type(4)));

#define B_SZ    1024
#define COUT_SZ 512
#define K_SZ    32768   // G * CIN
#define TM 128
#define TN 128
#define BK 32

// async 16B/lane global -> LDS DMA; lane l lands at base + 16*l.
__device__ __forceinline__ void async_copy16(const void* g, void* l) {
  __builtin_amdgcn_global_load_lds(
      (const __attribute__((address_space(1))) unsigned int*)g,
      (__attribute__((address_space(3))) unsigned int*)l, 16, 0, 0);
}

// ---------------------------------------------------------------------------
// Fused prep (one dispatch, block-split):
//   blocks [0, XCVT_BLOCKS):       x fp32 -> xb bf16 (same layout)
//   blocks [XCVT_BLOCKS, +4096):   W fp32 [k][o] -> Wt bf16 [o][k]
// Both memory-bound; fusing overlaps them across the device.
// ---------------------------------------------------------------------------
#define XCVT_BLOCKS 16384  // 33.5M elems / (256 thr * 8 elems)

__global__ __launch_bounds__(256) void prep_kernel(
    const float* __restrict__ x, __bf16* __restrict__ xb,
    const float* __restrict__ w, __bf16* __restrict__ wt) {
  __shared__ float t[64 * 65];  // pitch 65: <=2-way banks both phases
  int b = blockIdx.x;
  if (b < XCVT_BLOCKS) {
    const size_t i = ((size_t)b * 256 + threadIdx.x) * 8;
    f32x4 a = *(const f32x4*)(x + i);
    f32x4 c = *(const f32x4*)(x + i + 4);
    bf16x8 o;
#pragma unroll
    for (int e = 0; e < 4; ++e) {
      o[e]     = (__bf16)a[e];
      o[e + 4] = (__bf16)c[e];
    }
    *(bf16x8*)(xb + i) = o;
    return;  // no barrier on this path
  }
  b -= XCVT_BLOCKS;
  const int kb = (b & 511) * 64;   // K_SZ/64 = 512
  const int ob = (b >> 9) * 64;
  const int tid = threadIdx.x;
  {  // load 64x64 fp32 tile, coalesced 256B rows
    const int o4 = (tid & 15) * 4;
    const int kr = tid >> 4;
    const float* src = w + (size_t)(kb + kr) * COUT_SZ + ob + o4;
#pragma unroll
    for (int i = 0; i < 4; ++i) {
      f32x4 v = *(const f32x4*)(src + (size_t)(16 * i) * COUT_SZ);
      *(f32x4*)&t[(kr + 16 * i) * 65 + o4] = v;
    }
  }
  __syncthreads();
  {  // transposed store, coalesced 128B rows of Wt
    const int k4 = (tid & 15) * 4;
    const int orow = tid >> 4;
#pragma unroll
    for (int j = 0; j < 4; ++j) {
      const int o = orow + 16 * j;
      bf16x4 p;
#pragma unroll
      for (int e = 0; e < 4; ++e) p[e] = (__bf16)t[(k4 + e) * 65 + o];
      *(bf16x4*)(wt + (size_t)(ob + o) * K_SZ + kb + k4) = p;
    }
  }
}

// ---------------------------------------------------------------------------
// Split-K GEMM — m97-verified structure, cloned exactly:
// 128x128 tile, 256 thr (4 waves, each 64x64 = 4x4 frags of 16x16x32 bf16),
// BK=32, single-buffered 16 KB LDS, 2-barrier K-loop, 4 global_load_lds
// dwordx4 per block-iter, ~110 VGPR -> ~4 blocks/CU. Inter-BLOCK overlap
// (m114) is what hides the barrier vmcnt drain — R3's 1-block/CU dbuf
// removed it and ran 6 B/cyc/CU; m97's shape delivers 22.
//
// LDS: rows of 32 bf16 = 4 x 16B chunks; XOR swizzle phys = logical ^ (r&3),
// realized by permuting lanes' GLOBAL sources (DMA pins lane->LDS offset).
// Fragment reads then spread uniformly over the 8 quad-bank groups (floor).
//
// Block map lin = z + S*t: XCD = z%8 -> all 32 out-tiles of a z-group share
// one XCD's L2 (A-chunk x4, B-chunk x8 reuse; ~100 KB/iter working set).
// ---------------------------------------------------------------------------
__global__ __launch_bounds__(256, 3)
void gemm_kernel(const __bf16* __restrict__ xb, const __bf16* __restrict__ wt,
                 float* __restrict__ dst, int kchunk, int S) {
  __shared__ __bf16 As[TM * BK];  // 8 KB
  __shared__ __bf16 Bs[TN * BK];  // 8 KB

  const int lin = blockIdx.x;
  const int z = lin % S;
  const int t = lin / S;
  const int m0 = (t & 7) * TM;   // 8 m-tiles
  const int n0 = (t >> 3) * TN;  // 4 n-tiles
  const int tid  = threadIdx.x;
  const int w    = tid >> 6;
  const int lane = tid & 63;
  const int kbase = z * kchunk;

  // staging: wave w covers rows [w*32, w*32+32) of both tiles, 2 DMAs each.
  // DMA covers 16 rows x 4 chunks; lane l -> row l>>2, phys chunk l&3,
  // source logical chunk (l&3)^(row&3).
  const int sRow = lane >> 2;
  const int sCh  = (lane & 3) ^ (sRow & 3);
  const __bf16* ag0 = xb + (size_t)(m0 + w * 32 + sRow) * K_SZ + kbase + sCh * 8;
  const __bf16* ag1 = xb + (size_t)(m0 + w * 32 + 16 + sRow) * K_SZ + kbase + sCh * 8;
  const __bf16* bg0 = wt + (size_t)(n0 + w * 32 + sRow) * K_SZ + kbase + sCh * 8;
  const __bf16* bg1 = wt + (size_t)(n0 + w * 32 + 16 + sRow) * K_SZ + kbase + sCh * 8;
  __bf16* aL0 = &As[(w * 32) * BK];
  __bf16* aL1 = &As[(w * 32 + 16) * BK];
  __bf16* bL0 = &Bs[(w * 32) * BK];
  __bf16* bL1 = &Bs[(w * 32 + 16) * BK];

  // fragment geometry
  const int lm = lane & 15;
  const int q  = lane >> 4;
  const int wm = (w & 1) * 64;
  const int wn = (w >> 1) * 64;
  const int pc = q ^ (lm & 3);  // frag rows are wm/wn + i*16 + lm: row&3 == lm&3

  f32x4 acc[4][4];
#pragma unroll
  for (int i = 0; i < 4; ++i)
#pragma unroll
    for (int j = 0; j < 4; ++j)
      acc[i][j] = (f32x4){0.f, 0.f, 0.f, 0.f};

  const int niter = kchunk / BK;
  for (int it = 0; it < niter; ++it) {
    async_copy16(ag0, aL0);
    async_copy16(ag1, aL1);
    async_copy16(bg0, bL0);
    async_copy16(bg1, bL1);
    ag0 += BK; ag1 += BK; bg0 += BK; bg1 += BK;
    __syncthreads();  // drain DMA -> tiles valid

    bf16x8 af[4], bfr[4];
#pragma unroll
    for (int i = 0; i < 4; ++i)
      af[i] = *(const bf16x8*)&As[(wm + i * 16 + lm) * BK + pc * 8];
#pragma unroll
    for (int j = 0; j < 4; ++j)
      bfr[j] = *(const bf16x8*)&Bs[(wn + j * 16 + lm) * BK + pc * 8];

#pragma unroll
    for (int i = 0; i < 4; ++i)
#pragma unroll
      for (int j = 0; j < 4; ++j)
        acc[i][j] = __builtin_amdgcn_mfma_f32_16x16x32_bf16(af[i], bfr[j], acc[i][j], 0, 0, 0);

    __syncthreads();  // protect LDS from next staging
  }

  // epilogue: C/D layout col=lane&15, row=(lane>>4)*4+reg  [m89-verified]
  float* outp = dst + (size_t)z * (B_SZ * COUT_SZ)
              + (size_t)(m0 + wm + q * 4) * COUT_SZ + (n0 + wn + lm);
#pragma unroll
  for (int i = 0; i < 4; ++i) {
#pragma unroll
    for (int r = 0; r < 4; ++r) {
      float* o2 = outp + (size_t)(i * 16 + r) * COUT_SZ;
#pragma unroll
      for (int j = 0; j < 4; ++j)
        o2[j * 16] = acc[i][j][r];
    }
  }
}

// ---------------------------------------------------------------------------
// Reduce S partial slices + scale by 1/sqrt(512).
// ---------------------------------------------------------------------------
__global__ __launch_bounds__(256) void reduce_kernel(
    const float* __restrict__ p, float* __restrict__ out, int S, float scale) {
  const int i = (blockIdx.x * 256 + threadIdx.x) * 4;
  f32x4 s0 = (f32x4){0.f, 0.f, 0.f, 0.f};
  f32x4 s1 = (f32x4){0.f, 0.f, 0.f, 0.f};
  int zz = 0;
  for (; zz + 1 < S; zz += 2) {
    s0 = s0 + *(const f32x4*)(p + (size_t)zz * (B_SZ * COUT_SZ) + i);
    s1 = s1 + *(const f32x4*)(p + (size_t)(zz + 1) * (B_SZ * COUT_SZ) + i);
  }
  for (; zz < S; ++zz)
    s0 = s0 + *(const f32x4*)(p + (size_t)zz * (B_SZ * COUT_SZ) + i);
  s0 = (s0 + s1) * scale;
  *(f32x4*)(out + i) = s0;
}

extern "C" void kernel_launch(void* const* d_in, const int* in_sizes, int n_in,
                              void* d_out, int out_size, void* d_ws, size_t ws_size,
                              hipStream_t stream) {
  const float* x = (const float*)d_in[0];
  const float* w = (const float*)d_in[1];
  float* out = (float*)d_out;

  const size_t wtB    = (size_t)COUT_SZ * K_SZ * sizeof(__bf16);  // 33.5 MB
  const size_t xbB    = (size_t)B_SZ * K_SZ * sizeof(__bf16);     // 67 MB
  const size_t sliceB = (size_t)B_SZ * COUT_SZ * sizeof(float);   // 2 MB

  __bf16* wt = (__bf16*)d_ws;
  __bf16* xb = (__bf16*)((char*)d_ws + wtB);
  float* partials = (float*)((char*)d_ws + wtB + xbB);

  int S = 32;  // grid 1024 = 4 blocks/CU; kchunk 1024 (32 iters)
  while (S > 1 && wtB + xbB + (size_t)S * sliceB > ws_size) S >>= 1;
  if (wtB + xbB + sliceB > ws_size) { partials = out; S = 1; }  // last resort

  const float scale = 0.04419417382415922f;  // 1/sqrt(512)

  hipLaunchKernelGGL(prep_kernel, dim3(XCVT_BLOCKS + (K_SZ / 64) * (COUT_SZ / 64)),
                     dim3(256), 0, stream, x, xb, w, wt);
  hipLaunchKernelGGL(gemm_kernel, dim3(32 * S), dim3(256), 0, stream,
                     xb, wt, partials, K_SZ / S, S);
  hipLaunchKernelGGL(reduce_kernel, dim3(B_SZ * COUT_SZ / 1024), dim3(256), 0,
                     stream, partials, out, S, scale);
}